// Round 8
// baseline (4747.169 us; speedup 1.0000x reference)
//
#include <hip/hip_runtime.h>
#include <math.h>

// Problem constants
constexpr int Bc = 64, Tc = 512, Hc = 512, HEADSc = 4, Lc = 16, Rc = 256, Ac = 9;
constexpr int DH = 128;

#define F_BIAS   1
#define F_PE     2
#define F_ADDC   4
#define F_RELU   8
#define F_DIV    16
#define F_QKV    32
#define F_SPLITC 64

using short8   = __attribute__((ext_vector_type(8)))  short;
using floatx16 = __attribute__((ext_vector_type(16))) float;

// Exact 3-way bf16 split by mantissa truncation: v == hi + mid + lo exactly.
struct S3 { unsigned short h, m, l; };
__device__ inline S3 split3(float v)
{
    S3 r;
    unsigned u = __float_as_uint(v);
    r.h = (unsigned short)(u >> 16);
    float r1 = v - __uint_as_float(u & 0xffff0000u);
    unsigned u1 = __float_as_uint(r1);
    r.m = (unsigned short)(u1 >> 16);
    float r2 = r1 - __uint_as_float(u1 & 0xffff0000u);
    r.l = (unsigned short)(__float_as_uint(r2) >> 16);
    return r;
}

// ---------------------------------------------------------------------------
// MFMA bf16x6 GEMM, both operands pre-split. 128x128 tile, BK=32, 256 thr =
// 4 waves of 2x2 v_mfma_f32_32x32x16_bf16, 6 products (hh,hm,mh,hl,lh,mm).
// A planes: Asp[p*aPS + m*lda + k]; B planes: Bsp[p*bPS + n*ldb + k].
// Epilogues: fp32 C, or split-C (F_SPLITC), or QKV scatter (F_QKV).
// ---------------------------------------------------------------------------
__global__ __launch_bounds__(256)
void mgemm3(const unsigned short* __restrict__ Asp, long long aPS,
            const unsigned short* __restrict__ Bsp, long long bPS,
            float* __restrict__ C, unsigned short* __restrict__ Csp,
            long long cPS,
            const float* __restrict__ bias, const float* __restrict__ pe,
            int M, int N, int K, int lda, int ldb, int ldc,
            long long s1A, long long s2A, long long s1B, long long s2B,
            long long s1C, long long s2C, float divv, int flags)
{
    int z = blockIdx.z, z1 = z >> 2, z2 = z & 3;
    Asp += (size_t)z1 * s1A + (size_t)z2 * s2A;
    Bsp += (size_t)z1 * s1B + (size_t)z2 * s2B;
    if (!(flags & F_QKV)) {
        if (C)   C   += (size_t)z1 * s1C + (size_t)z2 * s2C;
        if (Csp) Csp += (size_t)z1 * s1C + (size_t)z2 * s2C;
    }

    __shared__ unsigned short As[3][128][40];
    __shared__ unsigned short Bs[3][128][40];

    int bm = blockIdx.y * 128, bn = blockIdx.x * 128;
    int tid = threadIdx.x;
    int lane = tid & 63, wave = tid >> 6;
    int wr = wave >> 1, wc = wave & 1;
    int l31 = lane & 31, khalf = lane >> 5;

    floatx16 acc[2][2];
    #pragma unroll
    for (int i = 0; i < 2; i++)
        #pragma unroll
        for (int j = 0; j < 2; j++)
            #pragma unroll
            for (int e = 0; e < 16; e++) acc[i][j][e] = 0.f;

    for (int k0 = 0; k0 < K; k0 += 32) {
        #pragma unroll
        for (int it = 0; it < 2; it++) {
            int s = tid + 256 * it;
            int rr = s >> 2, kc = (s & 3) << 3;
            size_t ga = (size_t)(bm + rr) * lda + k0 + kc;
            *(short8*)&As[0][rr][kc] = *(const short8*)(Asp + ga);
            *(short8*)&As[1][rr][kc] = *(const short8*)(Asp + aPS + ga);
            *(short8*)&As[2][rr][kc] = *(const short8*)(Asp + 2 * aPS + ga);
            size_t gb = (size_t)(bn + rr) * ldb + k0 + kc;
            *(short8*)&Bs[0][rr][kc] = *(const short8*)(Bsp + gb);
            *(short8*)&Bs[1][rr][kc] = *(const short8*)(Bsp + bPS + gb);
            *(short8*)&Bs[2][rr][kc] = *(const short8*)(Bsp + 2 * bPS + gb);
        }
        __syncthreads();

        #pragma unroll
        for (int s = 0; s < 2; s++) {
            int ko = s * 16 + khalf * 8;
            short8 a0[2], a1[2], a2[2], b0[2], b1[2], b2[2];
            #pragma unroll
            for (int i = 0; i < 2; i++) {
                int ar = wr * 64 + i * 32 + l31;
                a0[i] = *(const short8*)&As[0][ar][ko];
                a1[i] = *(const short8*)&As[1][ar][ko];
                a2[i] = *(const short8*)&As[2][ar][ko];
                int br = wc * 64 + i * 32 + l31;
                b0[i] = *(const short8*)&Bs[0][br][ko];
                b1[i] = *(const short8*)&Bs[1][br][ko];
                b2[i] = *(const short8*)&Bs[2][br][ko];
            }
            #pragma unroll
            for (int i = 0; i < 2; i++)
                #pragma unroll
                for (int j = 0; j < 2; j++)
                    acc[i][j] = __builtin_amdgcn_mfma_f32_32x32x16_bf16(a0[i], b0[j], acc[i][j], 0, 0, 0);
            #pragma unroll
            for (int i = 0; i < 2; i++)
                #pragma unroll
                for (int j = 0; j < 2; j++)
                    acc[i][j] = __builtin_amdgcn_mfma_f32_32x32x16_bf16(a0[i], b1[j], acc[i][j], 0, 0, 0);
            #pragma unroll
            for (int i = 0; i < 2; i++)
                #pragma unroll
                for (int j = 0; j < 2; j++)
                    acc[i][j] = __builtin_amdgcn_mfma_f32_32x32x16_bf16(a1[i], b0[j], acc[i][j], 0, 0, 0);
            #pragma unroll
            for (int i = 0; i < 2; i++)
                #pragma unroll
                for (int j = 0; j < 2; j++)
                    acc[i][j] = __builtin_amdgcn_mfma_f32_32x32x16_bf16(a0[i], b2[j], acc[i][j], 0, 0, 0);
            #pragma unroll
            for (int i = 0; i < 2; i++)
                #pragma unroll
                for (int j = 0; j < 2; j++)
                    acc[i][j] = __builtin_amdgcn_mfma_f32_32x32x16_bf16(a2[i], b0[j], acc[i][j], 0, 0, 0);
            #pragma unroll
            for (int i = 0; i < 2; i++)
                #pragma unroll
                for (int j = 0; j < 2; j++)
                    acc[i][j] = __builtin_amdgcn_mfma_f32_32x32x16_bf16(a1[i], b1[j], acc[i][j], 0, 0, 0);
        }
        __syncthreads();
    }

    // C/D layout: col=lane&31, row=(reg&3)+8*(reg>>2)+4*(lane>>5)
    #pragma unroll
    for (int i = 0; i < 2; i++) {
        #pragma unroll
        for (int j = 0; j < 2; j++) {
            #pragma unroll
            for (int r = 0; r < 16; r++) {
                int m = bm + wr * 64 + i * 32 + (r & 3) + ((r >> 2) << 3) + (khalf << 2);
                int n = bn + wc * 64 + j * 32 + l31;
                float v = acc[i][j][r];
                if (flags & F_DIV)  v /= divv;
                if (flags & F_BIAS) v += bias[n];
                if (flags & F_PE)   v += pe[(size_t)(m & (Tc - 1)) * Hc + n];
                if (flags & F_QKV) {
                    long long gth = s1C;   // group elems per plane
                    S3 sp = split3(v);
                    size_t o;
                    if (n < 512)       o = (size_t)m * 512 + n;
                    else if (n < 1024) o = 3 * gth + (size_t)m * 512 + (n - 512);
                    else               o = 6 * gth + (size_t)(m >> 9) * (Tc * Hc)
                                           + (size_t)(n - 1024) * 512 + (m & 511);
                    Csp[o] = sp.h; Csp[gth + o] = sp.m; Csp[2 * gth + o] = sp.l;
                } else if (flags & F_SPLITC) {
                    if (flags & F_RELU) v = fmaxf(v, 0.f);
                    S3 sp = split3(v);
                    size_t o = (size_t)m * ldc + n;
                    Csp[o] = sp.h; Csp[cPS + o] = sp.m; Csp[2 * cPS + o] = sp.l;
                } else {
                    if (flags & F_ADDC) v += C[(size_t)m * ldc + n];
                    if (flags & F_RELU) v = fmaxf(v, 0.f);
                    C[(size_t)m * ldc + n] = v;
                }
            }
        }
    }
}

// ---------------------------------------------------------------------------
// Activation split: X fp32 (E elems, row-major) -> 3 bf16 planes (stride PS).
// ---------------------------------------------------------------------------
__global__ __launch_bounds__(256)
void asplit_kernel(const float* __restrict__ X, unsigned short* __restrict__ out,
                   long long PS, long long E)
{
    long long off = ((long long)blockIdx.x * 256 + threadIdx.x) * 8;
    if (off >= E) return;
    float4 v0 = *(const float4*)(X + off);
    float4 v1 = *(const float4*)(X + off + 4);
    short8 h, m, l;
    float vv[8] = {v0.x, v0.y, v0.z, v0.w, v1.x, v1.y, v1.z, v1.w};
    #pragma unroll
    for (int i = 0; i < 8; i++) {
        S3 s = split3(vv[i]);
        h[i] = (short)s.h; m[i] = (short)s.m; l[i] = (short)s.l;
    }
    *(short8*)(out + off) = h;
    *(short8*)(out + PS + off) = m;
    *(short8*)(out + 2 * PS + off) = l;
}

// Weight pre-split: W [K][N] fp32 -> out[3][N][K] bf16 planes.
__global__ __launch_bounds__(256)
void wsplit_kernel(const float* __restrict__ W, unsigned short* __restrict__ out,
                   int K, int N, long long PS)
{
    __shared__ float t[64][65];
    int k0 = blockIdx.x * 64, n0 = blockIdx.y * 64;
    int tid = threadIdx.x;
    int c = tid & 63, r4 = tid >> 6;
    #pragma unroll
    for (int i = 0; i < 16; i++) {
        int r = r4 * 16 + i;
        t[r][c] = W[(size_t)(k0 + r) * N + n0 + c];
    }
    __syncthreads();
    #pragma unroll
    for (int i = 0; i < 16; i++) {
        int n = r4 * 16 + i;
        S3 s = split3(t[c][n]);
        size_t o = (size_t)(n0 + n) * K + k0 + c;
        out[o] = s.h; out[PS + o] = s.m; out[2 * PS + o] = s.l;
    }
}

// Positional encoding (float64 to match numpy promotion)
__global__ void pe_kernel(float* __restrict__ pe)
{
    int idx = blockIdx.x * 256 + threadIdx.x;
    if (idx >= Tc * Hc) return;
    int t = idx >> 9, n = idx & (Hc - 1);
    int j = n >> 1;
    double div = exp(-log(10000.0) * (double)(2 * j) / (double)Hc);
    double arg = (double)t * div;
    pe[idx] = (float)((n & 1) ? cos(arg) : sin(arg));
}

// a[m,n] = dot(accl[m,:9], W[:,n]) + bias[n] + pe[t,n]
__global__ __launch_bounds__(256)
void accl_kernel(const float* __restrict__ accl, const float* __restrict__ W,
                 const float* __restrict__ bias, const float* __restrict__ pe,
                 float* __restrict__ out)
{
    int idx = blockIdx.x * 256 + threadIdx.x;
    int n = idx & (Hc - 1);
    int m = idx >> 9;
    int t = m & (Tc - 1);
    const float* arow = accl + (size_t)m * Ac;
    float s = 0.f;
    #pragma unroll
    for (int i = 0; i < Ac; i++) s += arow[i] * W[i * Hc + n];
    s += bias[n];
    s += pe[t * Hc + n];
    out[idx] = s;
}

// x = dwconv(r, cr) + dwconv(a, ca), K=3, SAME
__global__ __launch_bounds__(256)
void dwconv_kernel(const float* __restrict__ r, const float* __restrict__ a,
                   const float* __restrict__ cr, const float* __restrict__ ca,
                   float* __restrict__ x)
{
    int idx = blockIdx.x * 256 + threadIdx.x;
    int c = idx & (Hc - 1);
    int m = idx >> 9;
    int t = m & (Tc - 1);
    float vr = r[idx] * cr[Hc + c];
    if (t > 0)      vr = r[idx - Hc] * cr[c] + vr;
    if (t < Tc - 1) vr = vr + r[idx + Hc] * cr[2 * Hc + c];
    float va = a[idx] * ca[Hc + c];
    if (t > 0)      va = a[idx - Hc] * ca[c] + va;
    if (t < Tc - 1) va = va + a[idx + Hc] * ca[2 * Hc + c];
    x[idx] = vr + va;
}

// row softmax over 512 cols, emitting split bf16 planes (PV A operand)
__global__ __launch_bounds__(256)
void softmax_split_kernel(const float* __restrict__ L,
                          unsigned short* __restrict__ Ps, long long PS)
{
    size_t base = (size_t)blockIdx.x * 512;
    int tid = threadIdx.x;
    float v0 = L[base + tid], v1 = L[base + tid + 256];
    __shared__ float buf[256];
    buf[tid] = fmaxf(v0, v1);
    __syncthreads();
    for (int s = 128; s > 0; s >>= 1) {
        if (tid < s) buf[tid] = fmaxf(buf[tid], buf[tid + s]);
        __syncthreads();
    }
    float mx = buf[0];
    __syncthreads();
    float e0 = expf(v0 - mx), e1 = expf(v1 - mx);
    buf[tid] = e0 + e1;
    __syncthreads();
    for (int s = 128; s > 0; s >>= 1) {
        if (tid < s) buf[tid] += buf[tid + s];
        __syncthreads();
    }
    float sum = buf[0];
    float p0 = e0 / sum, p1 = e1 / sum;
    S3 a = split3(p0), b = split3(p1);
    Ps[base + tid] = a.h; Ps[PS + base + tid] = a.m; Ps[2 * PS + base + tid] = a.l;
    Ps[base + tid + 256] = b.h; Ps[PS + base + tid + 256] = b.m;
    Ps[2 * PS + base + tid + 256] = b.l;
}

// out = LN(X + Y) * g + b (out may alias X)
__global__ __launch_bounds__(256)
void add_ln_kernel(const float* __restrict__ X, const float* __restrict__ Y,
                   const float* __restrict__ g, const float* __restrict__ bta,
                   float* __restrict__ out)
{
    size_t base = (size_t)blockIdx.x * 512;
    int tid = threadIdx.x;
    float v0 = X[base + tid] + Y[base + tid];
    float v1 = X[base + tid + 256] + Y[base + tid + 256];
    __shared__ float buf[256];
    buf[tid] = v0 + v1;
    __syncthreads();
    for (int s = 128; s > 0; s >>= 1) {
        if (tid < s) buf[tid] += buf[tid + s];
        __syncthreads();
    }
    float mean = buf[0] / 512.f;
    __syncthreads();
    float d0 = v0 - mean, d1 = v1 - mean;
    buf[tid] = d0 * d0 + d1 * d1;
    __syncthreads();
    for (int s = 128; s > 0; s >>= 1) {
        if (tid < s) buf[tid] += buf[tid + s];
        __syncthreads();
    }
    float var = buf[0] / 512.f;
    float rs = 1.0f / sqrtf(var + 1e-5f);
    out[base + tid]       = d0 * rs * g[tid] + bta[tid];
    out[base + tid + 256] = d1 * rs * g[tid + 256] + bta[tid + 256];
}

// em[m, l] = dot(X[m,:512], W[:,l]) + bias[l]; W cached in LDS
__global__ __launch_bounds__(256)
void em_kernel(const float* __restrict__ X, const float* __restrict__ W,
               const float* __restrict__ bias, float* __restrict__ out)
{
    __shared__ float Wl[8192];
    int tid = threadIdx.x;
    #pragma unroll
    for (int i = 0; i < 32; i++) Wl[tid + 256 * i] = W[tid + 256 * i];
    __syncthreads();
    int r = tid >> 4, l = tid & 15;
    const float* xr = X + ((size_t)blockIdx.x * 16 + r) * Hc;
    float s = 0.f;
    #pragma unroll 8
    for (int k = 0; k < Hc; k++) s += xr[k] * Wl[k * Lc + l];
    s += bias[l];
    out[((size_t)blockIdx.x * 16 + r) * Lc + l] = s;
}

// Viterbi: 1 wave/batch; score vector in registers (one per lane), all-gather
// via __shfl (no barrier on the step chain); em staged in 64-step LDS chunks.
// Exact numpy first-max semantics (strict >, serial index scan).
__global__ __launch_bounds__(64)
void viterbi_kernel(const float* __restrict__ em, const float* __restrict__ st,
                    const float* __restrict__ et, const float* __restrict__ trans,
                    int* __restrict__ out)
{
    int b = blockIdx.x;
    int tid = threadIdx.x;
    int j = tid & 15;
    __shared__ float ems[2][64][Lc];
    __shared__ unsigned char hist[Tc - 1][Lc];
    float trcol[Lc];
    #pragma unroll
    for (int i = 0; i < Lc; i++) trcol[i] = trans[i * Lc + j];
    const float* emb = em + (size_t)b * Tc * Lc;
    {
        const float4* src = (const float4*)emb;
        float4* dst = (float4*)&ems[0][0][0];
        #pragma unroll
        for (int i = 0; i < 4; i++) dst[tid + 64 * i] = src[tid + 64 * i];
    }
    __syncthreads();
    float sc = st[j] + ems[0][0][j];
    for (int c = 0; c < 8; c++) {
        if (c < 7) {
            const float4* src = (const float4*)(emb + (size_t)(c + 1) * 64 * Lc);
            float4* dst = (float4*)&ems[(c + 1) & 1][0][0];
            #pragma unroll
            for (int i = 0; i < 4; i++) dst[tid + 64 * i] = src[tid + 64 * i];
        }
        int tt0 = (c == 0) ? 1 : 0;
        for (int tt = tt0; tt < 64; tt++) {
            int t = c * 64 + tt;
            float e = ems[c & 1][tt][j];
            float best = (__shfl(sc, 0) + trcol[0]) + e;
            int bi = 0;
            #pragma unroll
            for (int i = 1; i < Lc; i++) {
                float v = (__shfl(sc, i) + trcol[i]) + e;
                if (v > best) { best = v; bi = i; }
            }
            sc = best;
            if (tid < Lc) hist[t - 1][j] = (unsigned char)bi;
        }
        __syncthreads();
    }
    // final argmax over sc + et (all lanes compute; lane 0 backtraces)
    float fv = sc + et[j];
    float bv = __shfl(fv, 0);
    int tag = 0;
    #pragma unroll
    for (int i = 1; i < Lc; i++) {
        float v = __shfl(fv, i);
        if (v > bv) { bv = v; tag = i; }
    }
    __syncthreads();
    if (tid == 0) {
        out[(size_t)b * Tc + (Tc - 1)] = tag;
        for (int t = Tc - 2; t >= 0; t--) {
            tag = hist[t][tag];
            out[(size_t)b * Tc + t] = tag;
        }
    }
}

__global__ void diag_kernel(int* __restrict__ out, int n, int val)
{
    int i = blockIdx.x * 256 + threadIdx.x;
    if (i < n) out[i] = val;
}

// ---------------------------------------------------------------------------
extern "C" void kernel_launch(void* const* d_in, const int* in_sizes, int n_in,
                              void* d_out, int out_size, void* d_ws, size_t ws_size,
                              hipStream_t stream)
{
    const float* rssi   = (const float*)d_in[0];
    const float* accl   = (const float*)d_in[1];
    const float* rssi_W = (const float*)d_in[2];
    const float* rssi_b = (const float*)d_in[3];
    const float* accl_W = (const float*)d_in[4];
    const float* accl_b = (const float*)d_in[5];
    const float* conv_r = (const float*)d_in[6];
    const float* conv_a = (const float*)d_in[7];
    const float* Wq     = (const float*)d_in[8];
    const float* Wk     = (const float*)d_in[9];
    const float* Wv     = (const float*)d_in[10];
    const float* Wo     = (const float*)d_in[11];
    const float* ln1_g  = (const float*)d_in[12];
    const float* ln1_b  = (const float*)d_in[13];
    const float* W1     = (const float*)d_in[14];
    const float* b1     = (const float*)d_in[15];
    const float* W2     = (const float*)d_in[16];
    const float* b2     = (const float*)d_in[17];
    const float* ln2_g  = (const float*)d_in[18];
    const float* ln2_b  = (const float*)d_in[19];
    const float* loc_W  = (const float*)d_in[20];
    const float* loc_b  = (const float*)d_in[21];
    const float* start_trans = (const float*)d_in[22];
    const float* end_trans   = (const float*)d_in[23];
    const float* trans       = (const float*)d_in[24];

    const int M = Bc * Tc;                        // 32768
    const size_t S = (size_t)M * Hc;              // 16,777,216 floats
    const size_t TH = (size_t)Tc * Hc;            // 262,144
    const long long TT = (long long)Tc * Tc;      // 262,144
    const float sq = sqrtf((float)DH);
    dim3 blk(256);

    const size_t WBUF_SH = 9830400ull;            // weight planes, shorts
    const size_t WBUF_F  = WBUF_SH / 2;
    size_t total_f = ws_size / sizeof(float);
    // Same floor as round 7 (known to pass): 2S + wbuf + pe + M*128
    if (total_f < 2 * S + WBUF_F + TH + (size_t)M * 128) {
        diag_kernel<<<dim3((out_size + 255) / 256), blk, 0, stream>>>(
            (int*)d_out, out_size, 1000000 + (int)(ws_size >> 20));
        return;
    }

    float* bufX = (float*)d_ws;
    float* bufY = bufX + S;
    unsigned short* wbuf  = (unsigned short*)(bufY + S);
    unsigned short* rssiT = wbuf;                 // [3][512n][256k]
    unsigned short* qkvT  = wbuf + 393216;        // [3][1536][512]
    unsigned short* WoT   = wbuf + 2752512;       // [3][512][512]
    unsigned short* W1T   = wbuf + 3538944;       // [3][2048][512]
    unsigned short* W2T   = wbuf + 6684672;       // [3][512][2048]
    float* pe_buf = (float*)(wbuf + WBUF_SH);
    float* work = pe_buf + TH;
    size_t work_n = total_f - 2 * S - WBUF_F - TH;   // >= M*128 = 4,194,304

    // Adaptive group sizes
    int Ge = 1;
    for (int g = 64; g >= 1; g >>= 1)
        if ((size_t)g * (196608 + TH) <= work_n) { Ge = g; break; }
    int Ga = 1;
    for (int g = 64; g >= 1; g >>= 1)
        if (16ull * g * TH <= work_n) { Ga = g; break; }
    int Mg = 1024, Nc = 512;
    for (int mg = 32768; mg >= 1024; mg >>= 1) {
        bool found = false;
        for (int nc = 2048; nc >= 512; nc >>= 1) {
            if (768ll * mg + (3ll * mg * nc) / 2 <= (long long)work_n) {
                Mg = mg; Nc = nc; found = true; break;
            }
        }
        if (found) break;
    }

    // ---- 0. pe + weight pre-split ----
    pe_kernel<<<dim3((Tc * Hc + 255) / 256), blk, 0, stream>>>(pe_buf);
    wsplit_kernel<<<dim3(Rc / 64, Hc / 64), blk, 0, stream>>>(rssi_W, rssiT, Rc, Hc, 131072LL);
    wsplit_kernel<<<dim3(8, 8),  blk, 0, stream>>>(Wq, qkvT,          512, 512, 786432LL);
    wsplit_kernel<<<dim3(8, 8),  blk, 0, stream>>>(Wk, qkvT + 262144, 512, 512, 786432LL);
    wsplit_kernel<<<dim3(8, 8),  blk, 0, stream>>>(Wv, qkvT + 524288, 512, 512, 786432LL);
    wsplit_kernel<<<dim3(8, 8),  blk, 0, stream>>>(Wo, WoT, 512, 512, 262144LL);
    wsplit_kernel<<<dim3(8, 32), blk, 0, stream>>>(W1, W1T, 512, 2048, 1048576LL);
    wsplit_kernel<<<dim3(32, 8), blk, 0, stream>>>(W2, W2T, 2048, 512, 1048576LL);

    // ---- 1. embed: a -> bufY (full); per Ge group: rssi split+gemm, conv ----
    accl_kernel<<<dim3(M * (Hc / 256)), blk, 0, stream>>>(accl, accl_W, accl_b, pe_buf, bufY);
    for (int g0 = 0; g0 < Bc; g0 += Ge) {
        int rows = Ge * Tc;
        long long rsPS = (long long)Ge * 131072;       // Ge*512*256 elems/plane
        unsigned short* rsS = (unsigned short*)work;
        float* rbuf = work + (size_t)Ge * 196608;      // 3*rsPS shorts
        asplit_kernel<<<dim3((unsigned)(3 * rsPS / 8 / 256 / 3 * 3 ? (rsPS / (8 * 256)) : 1)), blk, 0, stream>>>(
            rssi + (size_t)g0 * Tc * Rc, rsS, rsPS, rsPS);
        mgemm3<<<dim3(Hc / 128, rows / 128, 1), blk, 0, stream>>>(
            rsS, rsPS, rssiT, 131072LL,
            rbuf, nullptr, 0, rssi_b, pe_buf,
            rows, Hc, Rc, Rc, Rc, Hc,
            0, 0, 0, 0, 0, 0, 1.f, F_BIAS | F_PE);
        dwconv_kernel<<<dim3(rows * (Hc / 256)), blk, 0, stream>>>(
            rbuf, bufY + (size_t)g0 * TH, conv_r, conv_a, bufX + (size_t)g0 * TH);
    }

    // ---- 2. attention per batch-group Ga ----
    for (int g0 = 0; g0 < Bc; g0 += Ga) {
        int g = Ga;
        int rows = g * Tc;
        long long gth = (long long)g * TH;             // elems per plane
        unsigned short* qkvS = (unsigned short*)work;  // q(3)+k(3)+vT(3) planes
        unsigned short* xsS  = qkvS + 9 * gth;         // x split -> later os
        float* lg = work + 6 * gth;                    // fp32 logits, 4*gth
        unsigned short* PsS = (unsigned short*)(work + 10 * gth);  // 3 planes x 4*gth
        // split x for this group
        asplit_kernel<<<dim3((unsigned)(gth / (8 * 256))), blk, 0, stream>>>(
            bufX + (size_t)g0 * TH, xsS, gth, gth);
        // fused QKV (q,k split row-major; vT split transposed) via F_QKV
        mgemm3<<<dim3(1536 / 128, rows / 128, 1), blk, 0, stream>>>(
            xsS, gth, qkvT, 786432LL,
            nullptr, qkvS, 0, nullptr, nullptr,
            rows, 1536, Hc, Hc, 512, 0,
            0, 0, 0, 0, gth, 0, 1.f, F_QKV);
        // logits = q.k^T / sqrt(dh) (fp32 out)
        mgemm3<<<dim3(Tc / 128, Tc / 128, g * HEADSc), blk, 0, stream>>>(
            qkvS, gth, qkvS + 3 * gth, gth,
            lg, nullptr, 0, nullptr, nullptr,
            Tc, Tc, DH, 512, 512, Tc,
            (long long)TH, DH, (long long)TH, DH,
            (long long)HEADSc * TT, TT, sq, F_DIV);
        // softmax -> split P planes
        softmax_split_kernel<<<dim3(g * HEADSc * Tc), blk, 0, stream>>>(
            lg, PsS, 4 * gth);
        // o = P @ V -> split o planes (into xs slot)
        mgemm3<<<dim3(DH / 128, Tc / 128, g * HEADSc), blk, 0, stream>>>(
            PsS, 4 * gth, qkvS + 6 * gth, gth,
            nullptr, xsS, gth, nullptr, nullptr,
            Tc, DH, Tc, 512, 512, 512,
            (long long)HEADSc * TT, TT,
            (long long)TH, 65536LL,
            (long long)TH, 128LL, 1.f, F_SPLITC);
        // attn_out = o @ Wo (fp32 into bufY)
        mgemm3<<<dim3(Hc / 128, rows / 128, 1), blk, 0, stream>>>(
            xsS, gth, WoT, 262144LL,
            bufY + (size_t)g0 * TH, nullptr, 0, nullptr, nullptr,
            rows, Hc, Hc, 512, 512, Hc,
            0, 0, 0, 0, 0, 0, 1.f, 0);
    }

    // ---- 3. x1 = LN(x + attn_out) in-place in bufX ----
    add_ln_kernel<<<dim3(M), blk, 0, stream>>>(bufX, bufY, ln1_g, ln1_b, bufX);

    // ---- 4. FFN per m-group Mg, hidden chunked by Nc ----
    int nChunks = 2048 / Nc;
    for (int mg0 = 0; mg0 < M; mg0 += Mg) {
        long long x1PS = (long long)Mg * 512;
        unsigned short* x1S = (unsigned short*)work;
        unsigned short* hS  = x1S + 3 * x1PS;
        long long hPS = (long long)Mg * Nc;
        asplit_kernel<<<dim3((unsigned)(x1PS / (8 * 256))), blk, 0, stream>>>(
            bufX + (size_t)mg0 * 512, x1S, x1PS, x1PS);
        for (int c = 0; c < nChunks; c++) {
            mgemm3<<<dim3(Nc / 128, Mg / 128, 1), blk, 0, stream>>>(
                x1S, x1PS, W1T + (size_t)c * Nc * 512, 1048576LL,
                nullptr, hS, hPS, b1 + c * Nc, nullptr,
                Mg, Nc, Hc, 512, 512, Nc,
                0, 0, 0, 0, 0, 0, 1.f, F_BIAS | F_RELU | F_SPLITC);
            mgemm3<<<dim3(Hc / 128, Mg / 128, 1), blk, 0, stream>>>(
                hS, hPS, W2T + (size_t)c * Nc, 1048576LL,
                bufY + (size_t)mg0 * 512, nullptr, 0, b2, nullptr,
                Mg, Hc, Nc, Nc, 2048, Hc,
                0, 0, 0, 0, 0, 0, 1.f, (c == 0) ? F_BIAS : F_ADDC);
        }
    }

    // ---- 5. x2 = LN(x1 + f) in-place in bufX ----
    add_ln_kernel<<<dim3(M), blk, 0, stream>>>(bufX, bufY, ln2_g, ln2_b, bufX);

    // ---- 6. emissions ----
    em_kernel<<<dim3(M / 16), blk, 0, stream>>>(bufX, loc_W, loc_b, work);

    // ---- 7. viterbi ----
    viterbi_kernel<<<dim3(Bc), dim3(64), 0, stream>>>(
        work, start_trans, end_trans, trans, (int*)d_out);
}

// Round 9
// 3143.304 us; speedup vs baseline: 1.5102x; 1.5102x over previous
//
#include <hip/hip_runtime.h>
#include <math.h>

// Problem constants
constexpr int Bc = 64, Tc = 512, Hc = 512, HEADSc = 4, Lc = 16, Rc = 256, Ac = 9;
constexpr int DH = 128;

#define F_BIAS 1
#define F_PE   2
#define F_ADDC 4
#define F_RELU 8
#define F_DIV  16
#define F_QKV  32

using short8   = __attribute__((ext_vector_type(8)))  short;
using floatx16 = __attribute__((ext_vector_type(16))) float;
using ushort4v = __attribute__((ext_vector_type(4)))  unsigned short;

// Exact 3-way bf16 split by mantissa truncation: v == hi + mid + lo exactly.
struct S3 { unsigned short h, m, l; };
__device__ inline S3 split3(float v)
{
    S3 r;
    unsigned u = __float_as_uint(v);
    r.h = (unsigned short)(u >> 16);
    float r1 = v - __uint_as_float(u & 0xffff0000u);
    unsigned u1 = __float_as_uint(r1);
    r.m = (unsigned short)(u1 >> 16);
    float r2 = r1 - __uint_as_float(u1 & 0xffff0000u);
    r.l = (unsigned short)(__float_as_uint(r2) >> 16);
    return r;
}

// ---------------------------------------------------------------------------
// MFMA bf16x6 GEMM. 128x128 tile, BK=32, 256 thr = 4 waves of 2x2
// v_mfma_f32_32x32x16_bf16, 6 products (hh,hm,mh,hl,lh,mm; err ~2^-24).
// A: ASP ? pre-split planes Asp (stride aPS) : fp32 Af split in-kernel.
// B: BSP ? pre-split planes Bsp (stride bPS) : fp32 Bf [n][k] split in-kernel.
// ---------------------------------------------------------------------------
template<bool ASP, bool BSP>
__global__ __launch_bounds__(256)
void mgemm(const float* __restrict__ Af, const unsigned short* __restrict__ Asp,
           long long aPS,
           const float* __restrict__ Bf, const unsigned short* __restrict__ Bsp,
           long long bPS,
           float* __restrict__ C, const float* __restrict__ bias,
           const float* __restrict__ pe,
           int M, int N, int K, int lda, int ldb, int ldc,
           long long s1A, long long s2A, long long s1B, long long s2B,
           long long s1C, long long s2C, float divv, int flags)
{
    int z = blockIdx.z, z1 = z >> 2, z2 = z & 3;
    if (ASP) Asp += (size_t)z1 * s1A + (size_t)z2 * s2A;
    else     Af  += (size_t)z1 * s1A + (size_t)z2 * s2A;
    if (BSP) Bsp += (size_t)z1 * s1B + (size_t)z2 * s2B;
    else     Bf  += (size_t)z1 * s1B + (size_t)z2 * s2B;
    if (!(flags & F_QKV)) C += (size_t)z1 * s1C + (size_t)z2 * s2C;

    __shared__ unsigned short As[3][128][40];
    __shared__ unsigned short Bs[3][128][40];

    int bm = blockIdx.y * 128, bn = blockIdx.x * 128;
    int tid = threadIdx.x;
    int lane = tid & 63, wave = tid >> 6;
    int wr = wave >> 1, wc = wave & 1;
    int l31 = lane & 31, khalf = lane >> 5;

    floatx16 acc[2][2];
    #pragma unroll
    for (int i = 0; i < 2; i++)
        #pragma unroll
        for (int j = 0; j < 2; j++)
            #pragma unroll
            for (int e = 0; e < 16; e++) acc[i][j][e] = 0.f;

    for (int k0 = 0; k0 < K; k0 += 32) {
        // ---- stage A ----
        if (ASP) {
            #pragma unroll
            for (int it = 0; it < 2; it++) {
                int s = tid + 256 * it;
                int rr = s >> 2, kc = (s & 3) << 3;
                size_t ga = (size_t)(bm + rr) * lda + k0 + kc;
                *(short8*)&As[0][rr][kc] = *(const short8*)(Asp + ga);
                *(short8*)&As[1][rr][kc] = *(const short8*)(Asp + aPS + ga);
                *(short8*)&As[2][rr][kc] = *(const short8*)(Asp + 2 * aPS + ga);
            }
        } else {
            #pragma unroll
            for (int it = 0; it < 4; it++) {
                int s = tid + 256 * it;
                int mm = s >> 3, kc = (s & 7) << 2;
                float4 v = *(const float4*)(Af + (size_t)(bm + mm) * lda + k0 + kc);
                ushort4v h, m, l;
                S3 s0 = split3(v.x); h[0] = s0.h; m[0] = s0.m; l[0] = s0.l;
                S3 s1 = split3(v.y); h[1] = s1.h; m[1] = s1.m; l[1] = s1.l;
                S3 s2 = split3(v.z); h[2] = s2.h; m[2] = s2.m; l[2] = s2.l;
                S3 s3 = split3(v.w); h[3] = s3.h; m[3] = s3.m; l[3] = s3.l;
                *(ushort4v*)&As[0][mm][kc] = h;
                *(ushort4v*)&As[1][mm][kc] = m;
                *(ushort4v*)&As[2][mm][kc] = l;
            }
        }
        // ---- stage B ----
        if (BSP) {
            #pragma unroll
            for (int it = 0; it < 2; it++) {
                int s = tid + 256 * it;
                int nn = s >> 2, kc = (s & 3) << 3;
                size_t go = (size_t)(bn + nn) * ldb + k0 + kc;
                *(short8*)&Bs[0][nn][kc] = *(const short8*)(Bsp + go);
                *(short8*)&Bs[1][nn][kc] = *(const short8*)(Bsp + bPS + go);
                *(short8*)&Bs[2][nn][kc] = *(const short8*)(Bsp + 2 * bPS + go);
            }
        } else {
            #pragma unroll
            for (int it = 0; it < 4; it++) {
                int s = tid + 256 * it;
                int nn = s >> 3, kc = (s & 7) << 2;
                float4 v = *(const float4*)(Bf + (size_t)(bn + nn) * ldb + k0 + kc);
                ushort4v h, m, l;
                S3 s0 = split3(v.x); h[0] = s0.h; m[0] = s0.m; l[0] = s0.l;
                S3 s1 = split3(v.y); h[1] = s1.h; m[1] = s1.m; l[1] = s1.l;
                S3 s2 = split3(v.z); h[2] = s2.h; m[2] = s2.m; l[2] = s2.l;
                S3 s3 = split3(v.w); h[3] = s3.h; m[3] = s3.m; l[3] = s3.l;
                *(ushort4v*)&Bs[0][nn][kc] = h;
                *(ushort4v*)&Bs[1][nn][kc] = m;
                *(ushort4v*)&Bs[2][nn][kc] = l;
            }
        }
        __syncthreads();

        #pragma unroll
        for (int s = 0; s < 2; s++) {
            int ko = s * 16 + khalf * 8;
            short8 a0[2], a1[2], a2[2], b0[2], b1[2], b2[2];
            #pragma unroll
            for (int i = 0; i < 2; i++) {
                int ar = wr * 64 + i * 32 + l31;
                a0[i] = *(const short8*)&As[0][ar][ko];
                a1[i] = *(const short8*)&As[1][ar][ko];
                a2[i] = *(const short8*)&As[2][ar][ko];
                int br = wc * 64 + i * 32 + l31;
                b0[i] = *(const short8*)&Bs[0][br][ko];
                b1[i] = *(const short8*)&Bs[1][br][ko];
                b2[i] = *(const short8*)&Bs[2][br][ko];
            }
            #pragma unroll
            for (int i = 0; i < 2; i++)
                #pragma unroll
                for (int j = 0; j < 2; j++)
                    acc[i][j] = __builtin_amdgcn_mfma_f32_32x32x16_bf16(a0[i], b0[j], acc[i][j], 0, 0, 0);
            #pragma unroll
            for (int i = 0; i < 2; i++)
                #pragma unroll
                for (int j = 0; j < 2; j++)
                    acc[i][j] = __builtin_amdgcn_mfma_f32_32x32x16_bf16(a0[i], b1[j], acc[i][j], 0, 0, 0);
            #pragma unroll
            for (int i = 0; i < 2; i++)
                #pragma unroll
                for (int j = 0; j < 2; j++)
                    acc[i][j] = __builtin_amdgcn_mfma_f32_32x32x16_bf16(a1[i], b0[j], acc[i][j], 0, 0, 0);
            #pragma unroll
            for (int i = 0; i < 2; i++)
                #pragma unroll
                for (int j = 0; j < 2; j++)
                    acc[i][j] = __builtin_amdgcn_mfma_f32_32x32x16_bf16(a0[i], b2[j], acc[i][j], 0, 0, 0);
            #pragma unroll
            for (int i = 0; i < 2; i++)
                #pragma unroll
                for (int j = 0; j < 2; j++)
                    acc[i][j] = __builtin_amdgcn_mfma_f32_32x32x16_bf16(a2[i], b0[j], acc[i][j], 0, 0, 0);
            #pragma unroll
            for (int i = 0; i < 2; i++)
                #pragma unroll
                for (int j = 0; j < 2; j++)
                    acc[i][j] = __builtin_amdgcn_mfma_f32_32x32x16_bf16(a1[i], b1[j], acc[i][j], 0, 0, 0);
        }
        __syncthreads();
    }

    // C/D layout: col=lane&31, row=(reg&3)+8*(reg>>2)+4*(lane>>5)
    #pragma unroll
    for (int i = 0; i < 2; i++) {
        #pragma unroll
        for (int j = 0; j < 2; j++) {
            #pragma unroll
            for (int r = 0; r < 16; r++) {
                int m = bm + wr * 64 + i * 32 + (r & 3) + ((r >> 2) << 3) + (khalf << 2);
                int n = bn + wc * 64 + j * 32 + l31;
                float v = acc[i][j][r];
                if (flags & F_DIV)  v /= divv;
                if (flags & F_BIAS) v += bias[n];
                if (flags & F_PE)   v += pe[(size_t)(m & (Tc - 1)) * Hc + n];
                if (flags & F_QKV) {
                    long long gth = s1C;  // group plane elems carried via s1C
                    if (n < 512) {
                        C[(size_t)m * 512 + n] = v;
                    } else if (n < 1024) {
                        C[gth + (size_t)m * 512 + (n - 512)] = v;
                    } else {
                        // V stored transposed: [b][h*128+d][t], fp32
                        C[2 * gth + (size_t)(m >> 9) * (Tc * Hc)
                          + (size_t)(n - 1024) * Tc + (m & (Tc - 1))] = v;
                    }
                } else {
                    if (flags & F_ADDC) v += C[(size_t)m * ldc + n];
                    if (flags & F_RELU) v = fmaxf(v, 0.f);
                    C[(size_t)m * ldc + n] = v;
                }
            }
        }
    }
}

// Activation split: X fp32 (E elems) -> 3 bf16 planes (stride PS elems).
__global__ __launch_bounds__(256)
void asplit_kernel(const float* __restrict__ X, unsigned short* __restrict__ out,
                   long long PS, long long E)
{
    long long off = ((long long)blockIdx.x * 256 + threadIdx.x) * 8;
    if (off >= E) return;
    float4 v0 = *(const float4*)(X + off);
    float4 v1 = *(const float4*)(X + off + 4);
    short8 h, m, l;
    float vv[8] = {v0.x, v0.y, v0.z, v0.w, v1.x, v1.y, v1.z, v1.w};
    #pragma unroll
    for (int i = 0; i < 8; i++) {
        S3 s = split3(vv[i]);
        h[i] = (short)s.h; m[i] = (short)s.m; l[i] = (short)s.l;
    }
    *(short8*)(out + off) = h;
    *(short8*)(out + PS + off) = m;
    *(short8*)(out + 2 * PS + off) = l;
}

// Weight pre-split: W [K][N] fp32 -> out[3][N][K] bf16 planes.
__global__ __launch_bounds__(256)
void wsplit_kernel(const float* __restrict__ W, unsigned short* __restrict__ out,
                   int K, int N, long long PS)
{
    __shared__ float t[64][65];
    int k0 = blockIdx.x * 64, n0 = blockIdx.y * 64;
    int tid = threadIdx.x;
    int c = tid & 63, r4 = tid >> 6;
    #pragma unroll
    for (int i = 0; i < 16; i++) {
        int r = r4 * 16 + i;
        t[r][c] = W[(size_t)(k0 + r) * N + n0 + c];
    }
    __syncthreads();
    #pragma unroll
    for (int i = 0; i < 16; i++) {
        int n = r4 * 16 + i;
        S3 s = split3(t[c][n]);
        size_t o = (size_t)(n0 + n) * K + k0 + c;
        out[o] = s.h; out[PS + o] = s.m; out[2 * PS + o] = s.l;
    }
}

// Positional encoding (float64 to match numpy promotion)
__global__ void pe_kernel(float* __restrict__ pe)
{
    int idx = blockIdx.x * 256 + threadIdx.x;
    if (idx >= Tc * Hc) return;
    int t = idx >> 9, n = idx & (Hc - 1);
    int j = n >> 1;
    double div = exp(-log(10000.0) * (double)(2 * j) / (double)Hc);
    double arg = (double)t * div;
    pe[idx] = (float)((n & 1) ? cos(arg) : sin(arg));
}

// Fused: x = dwconv(r, cr) + dwconv(a, ca), where a is recomputed on the fly
// from accl (9-dim) + bias + pe.  Saves the full a materialization pass.
__global__ __launch_bounds__(256)
void dwconv_fused_kernel(const float* __restrict__ r,
                         const float* __restrict__ accl,
                         const float* __restrict__ aW, const float* __restrict__ ab,
                         const float* __restrict__ pe,
                         const float* __restrict__ cr, const float* __restrict__ ca,
                         float* __restrict__ x)
{
    int idx = blockIdx.x * 256 + threadIdx.x;
    int c = idx & (Hc - 1);
    int m = idx >> 9;
    int t = m & (Tc - 1);
    float w[Ac];
    #pragma unroll
    for (int i = 0; i < Ac; i++) w[i] = aW[i * Hc + c];
    float bb = ab[c];

    auto aval = [&](int mm, int tt) {
        const float* row = accl + (size_t)mm * Ac;
        float s = 0.f;
        #pragma unroll
        for (int i = 0; i < Ac; i++) s += row[i] * w[i];
        return s + bb + pe[tt * Hc + c];
    };

    float vr = r[idx] * cr[Hc + c];
    float va = aval(m, t) * ca[Hc + c];
    if (t > 0) {
        vr = r[idx - Hc] * cr[c] + vr;
        va = aval(m - 1, t - 1) * ca[c] + va;
    }
    if (t < Tc - 1) {
        vr = vr + r[idx + Hc] * cr[2 * Hc + c];
        va = va + aval(m + 1, t + 1) * ca[2 * Hc + c];
    }
    x[idx] = vr + va;
}

// in-place row softmax over 512 columns, one block per row
__global__ __launch_bounds__(256)
void softmax_kernel(float* __restrict__ L)
{
    size_t base = (size_t)blockIdx.x * 512;
    int tid = threadIdx.x;
    float v0 = L[base + tid], v1 = L[base + tid + 256];
    __shared__ float buf[256];
    buf[tid] = fmaxf(v0, v1);
    __syncthreads();
    for (int s = 128; s > 0; s >>= 1) {
        if (tid < s) buf[tid] = fmaxf(buf[tid], buf[tid + s]);
        __syncthreads();
    }
    float mx = buf[0];
    __syncthreads();
    float e0 = expf(v0 - mx), e1 = expf(v1 - mx);
    buf[tid] = e0 + e1;
    __syncthreads();
    for (int s = 128; s > 0; s >>= 1) {
        if (tid < s) buf[tid] += buf[tid + s];
        __syncthreads();
    }
    float sum = buf[0];
    L[base + tid] = e0 / sum;
    L[base + tid + 256] = e1 / sum;
}

// out = LN(X + Y) * g + b (out may alias X)
__global__ __launch_bounds__(256)
void add_ln_kernel(const float* __restrict__ X, const float* __restrict__ Y,
                   const float* __restrict__ g, const float* __restrict__ bta,
                   float* __restrict__ out)
{
    size_t base = (size_t)blockIdx.x * 512;
    int tid = threadIdx.x;
    float v0 = X[base + tid] + Y[base + tid];
    float v1 = X[base + tid + 256] + Y[base + tid + 256];
    __shared__ float buf[256];
    buf[tid] = v0 + v1;
    __syncthreads();
    for (int s = 128; s > 0; s >>= 1) {
        if (tid < s) buf[tid] += buf[tid + s];
        __syncthreads();
    }
    float mean = buf[0] / 512.f;
    __syncthreads();
    float d0 = v0 - mean, d1 = v1 - mean;
    buf[tid] = d0 * d0 + d1 * d1;
    __syncthreads();
    for (int s = 128; s > 0; s >>= 1) {
        if (tid < s) buf[tid] += buf[tid + s];
        __syncthreads();
    }
    float var = buf[0] / 512.f;
    float rs = 1.0f / sqrtf(var + 1e-5f);
    out[base + tid]       = d0 * rs * g[tid] + bta[tid];
    out[base + tid + 256] = d1 * rs * g[tid + 256] + bta[tid + 256];
}

// em[m, l] = dot(X[m,:512], W[:,l]) + bias[l]; W cached in LDS
__global__ __launch_bounds__(256)
void em_kernel(const float* __restrict__ X, const float* __restrict__ W,
               const float* __restrict__ bias, float* __restrict__ out)
{
    __shared__ float Wl[8192];
    int tid = threadIdx.x;
    #pragma unroll
    for (int i = 0; i < 32; i++) Wl[tid + 256 * i] = W[tid + 256 * i];
    __syncthreads();
    int r = tid >> 4, l = tid & 15;
    const float* xr = X + ((size_t)blockIdx.x * 16 + r) * Hc;
    float s = 0.f;
    #pragma unroll 8
    for (int k = 0; k < Hc; k++) s += xr[k] * Wl[k * Lc + l];
    s += bias[l];
    out[((size_t)blockIdx.x * 16 + r) * Lc + l] = s;
}

// ---------------------------------------------------------------------------
// Viterbi: 1 wave/batch. Lane (q=lane>>4, j=lane&15) evaluates sources
// i in {4q..4q+3}; first-max argmax via u64 packing (ordered_float<<8)|(15-i)
// — ties resolve to smallest i exactly like numpy. Cross-q: 2 shfl_xor.
// em staged to LDS in 64-step double-buffered chunks.
// ---------------------------------------------------------------------------
__device__ inline unsigned long long vit_pack(float v, int idx)
{
    unsigned u = __float_as_uint(v);
    unsigned ou = (u & 0x80000000u) ? ~u : (u | 0x80000000u);
    return ((unsigned long long)ou << 8) | (unsigned)idx;
}
__device__ inline float vit_unpack(unsigned long long p)
{
    unsigned ou = (unsigned)(p >> 8);
    unsigned u = (ou & 0x80000000u) ? (ou & 0x7fffffffu) : ~ou;
    return __uint_as_float(u);
}

__global__ __launch_bounds__(64)
void viterbi_kernel(const float* __restrict__ em, const float* __restrict__ st,
                    const float* __restrict__ et, const float* __restrict__ trans,
                    int* __restrict__ out)
{
    int b = blockIdx.x;
    int tid = threadIdx.x;
    int j = tid & 15, q = tid >> 4;
    __shared__ float ems[2][64][Lc];
    __shared__ unsigned char hist[Tc - 1][Lc];
    float tr0 = trans[(4 * q + 0) * Lc + j];
    float tr1 = trans[(4 * q + 1) * Lc + j];
    float tr2 = trans[(4 * q + 2) * Lc + j];
    float tr3 = trans[(4 * q + 3) * Lc + j];
    const float* emb = em + (size_t)b * Tc * Lc;
    {
        const float4* src = (const float4*)emb;
        float4* dst = (float4*)&ems[0][0][0];
        #pragma unroll
        for (int i = 0; i < 4; i++) dst[tid + 64 * i] = src[tid + 64 * i];
    }
    __syncthreads();
    float sc = st[j] + ems[0][0][j];
    for (int c = 0; c < 8; c++) {
        if (c < 7) {
            const float4* src = (const float4*)(emb + (size_t)(c + 1) * 64 * Lc);
            float4* dst = (float4*)&ems[(c + 1) & 1][0][0];
            #pragma unroll
            for (int i = 0; i < 4; i++) dst[tid + 64 * i] = src[tid + 64 * i];
        }
        int tt0 = (c == 0) ? 1 : 0;
        for (int tt = tt0; tt < 64; tt++) {
            int t = c * 64 + tt;
            float e = ems[c & 1][tt][j];
            float s0 = __shfl(sc, 4 * q + 0);
            float s1 = __shfl(sc, 4 * q + 1);
            float s2 = __shfl(sc, 4 * q + 2);
            float s3 = __shfl(sc, 4 * q + 3);
            unsigned long long p = vit_pack((s0 + tr0) + e, 15 - (4 * q + 0));
            unsigned long long p1 = vit_pack((s1 + tr1) + e, 15 - (4 * q + 1));
            unsigned long long p2 = vit_pack((s2 + tr2) + e, 15 - (4 * q + 2));
            unsigned long long p3 = vit_pack((s3 + tr3) + e, 15 - (4 * q + 3));
            if (p1 > p) p = p1;
            if (p2 > p) p = p2;
            if (p3 > p) p = p3;
            unsigned long long po = __shfl_xor(p, 16);
            if (po > p) p = po;
            po = __shfl_xor(p, 32);
            if (po > p) p = po;
            sc = vit_unpack(p);
            if (q == 0) hist[t - 1][j] = (unsigned char)(15 - (int)(p & 0xFF));
        }
        __syncthreads();
    }
    float fv = sc + et[j];
    float bv = __shfl(fv, 0);
    int tag = 0;
    #pragma unroll
    for (int i = 1; i < Lc; i++) {
        float v = __shfl(fv, i);
        if (v > bv) { bv = v; tag = i; }
    }
    __syncthreads();
    if (tid == 0) {
        out[(size_t)b * Tc + (Tc - 1)] = tag;
        for (int t = Tc - 2; t >= 0; t--) {
            tag = hist[t][tag];
            out[(size_t)b * Tc + t] = tag;
        }
    }
}

__global__ void diag_kernel(int* __restrict__ out, int n, int val)
{
    int i = blockIdx.x * 256 + threadIdx.x;
    if (i < n) out[i] = val;
}

// ---------------------------------------------------------------------------
extern "C" void kernel_launch(void* const* d_in, const int* in_sizes, int n_in,
                              void* d_out, int out_size, void* d_ws, size_t ws_size,
                              hipStream_t stream)
{
    const float* rssi   = (const float*)d_in[0];
    const float* accl   = (const float*)d_in[1];
    const float* rssi_W = (const float*)d_in[2];
    const float* rssi_b = (const float*)d_in[3];
    const float* accl_W = (const float*)d_in[4];
    const float* accl_b = (const float*)d_in[5];
    const float* conv_r = (const float*)d_in[6];
    const float* conv_a = (const float*)d_in[7];
    const float* Wq     = (const float*)d_in[8];
    const float* Wk     = (const float*)d_in[9];
    const float* Wv     = (const float*)d_in[10];
    const float* Wo     = (const float*)d_in[11];
    const float* ln1_g  = (const float*)d_in[12];
    const float* ln1_b  = (const float*)d_in[13];
    const float* W1     = (const float*)d_in[14];
    const float* b1     = (const float*)d_in[15];
    const float* W2     = (const float*)d_in[16];
    const float* b2     = (const float*)d_in[17];
    const float* ln2_g  = (const float*)d_in[18];
    const float* ln2_b  = (const float*)d_in[19];
    const float* loc_W  = (const float*)d_in[20];
    const float* loc_b  = (const float*)d_in[21];
    const float* start_trans = (const float*)d_in[22];
    const float* end_trans   = (const float*)d_in[23];
    const float* trans       = (const float*)d_in[24];

    const int M = Bc * Tc;                        // 32768
    const size_t S = (size_t)M * Hc;              // 16,777,216 floats
    const size_t TH = (size_t)Tc * Hc;            // 262,144
    const long long TT = (long long)Tc * Tc;
    const float sq = sqrtf((float)DH);
    dim3 blk(256);

    const size_t WBUF_SH = 9830400ull;            // weight planes, shorts
    const size_t WBUF_F  = WBUF_SH / 2;
    size_t total_f = ws_size / sizeof(float);
    if (total_f < 2 * S + WBUF_F + TH + (size_t)M * 128) {
        diag_kernel<<<dim3((out_size + 255) / 256), blk, 0, stream>>>(
            (int*)d_out, out_size, 1000000 + (int)(ws_size >> 20));
        return;
    }

    float* bufX = (float*)d_ws;
    float* bufY = bufX + S;
    unsigned short* wbuf  = (unsigned short*)(bufY + S);
    unsigned short* rssiT = wbuf;                 // [3][512n][256k]
    unsigned short* qkvT  = wbuf + 393216;        // [3][1536][512]
    unsigned short* WoT   = wbuf + 2752512;       // [3][512][512]
    unsigned short* W1T   = wbuf + 3538944;       // [3][2048][512]
    unsigned short* W2T   = wbuf + 6684672;       // [3][512][2048]
    float* pe_buf = (float*)(wbuf + WBUF_SH);
    float* work = pe_buf + TH;
    size_t work_n = total_f - 2 * S - WBUF_F - TH;   // >= M*128

    // Group sizes
    int Ge = 1;
    for (int g = 64; g >= 1; g >>= 1) if ((size_t)g * TH <= work_n) { Ge = g; break; }
    int Ga = 1;
    for (int g = 64; g >= 1; g >>= 1)
        if ((19ull * g * TH) / 2 <= work_n) { Ga = g; break; }
    // FFN: optionally pre-split x1 (x1S = 3*M*512 shorts = 25,165,824 floats)
    const size_t X1S_F = 25165824ull;
    bool ASP1 = (work_n >= X1S_F + (size_t)M * 128);
    int Nc = 128;
    {
        size_t base = ASP1 ? X1S_F : 0;
        for (int n = 2048; n >= 128; n >>= 1)
            if (base + (size_t)M * n <= work_n) { Nc = n; break; }
    }

    // ---- 0. pe + weight pre-split ----
    pe_kernel<<<dim3((Tc * Hc + 255) / 256), blk, 0, stream>>>(pe_buf);
    wsplit_kernel<<<dim3(Rc / 64, Hc / 64), blk, 0, stream>>>(rssi_W, rssiT, Rc, Hc, 131072LL);
    wsplit_kernel<<<dim3(8, 8),  blk, 0, stream>>>(Wq, qkvT,          512, 512, 786432LL);
    wsplit_kernel<<<dim3(8, 8),  blk, 0, stream>>>(Wk, qkvT + 262144, 512, 512, 786432LL);
    wsplit_kernel<<<dim3(8, 8),  blk, 0, stream>>>(Wv, qkvT + 524288, 512, 512, 786432LL);
    wsplit_kernel<<<dim3(8, 8),  blk, 0, stream>>>(Wo, WoT, 512, 512, 262144LL);
    wsplit_kernel<<<dim3(8, 32), blk, 0, stream>>>(W1, W1T, 512, 2048, 1048576LL);
    wsplit_kernel<<<dim3(32, 8), blk, 0, stream>>>(W2, W2T, 2048, 512, 1048576LL);

    // ---- 1. embed per Ge group: rssi gemm -> work (r); fused conv -> bufX ----
    for (int g0 = 0; g0 < Bc; g0 += Ge) {
        int rows = Ge * Tc;
        mgemm<false, true><<<dim3(Hc / 128, rows / 128, 1), blk, 0, stream>>>(
            rssi + (size_t)g0 * Tc * Rc, nullptr, 0,
            nullptr, rssiT, 131072LL,
            work, rssi_b, pe_buf,
            rows, Hc, Rc, Rc, Rc, Hc,
            0, 0, 0, 0, 0, 0, 1.f, F_BIAS | F_PE);
        dwconv_fused_kernel<<<dim3(rows * (Hc / 256)), blk, 0, stream>>>(
            work, accl + (size_t)g0 * Tc * Ac, accl_W, accl_b, pe_buf,
            conv_r, conv_a, bufX + (size_t)g0 * TH);
    }

    // ---- 2. attention per Ga group ----
    for (int g0 = 0; g0 < Bc; g0 += Ga) {
        int g = Ga;
        int rows = g * Tc;
        long long gth = (long long)g * TH;
        float* qg = work;                  // [rows][512]
        float* kg = work + gth;
        float* vT = work + 2 * gth;        // [b][d][t] fp32
        float* og = work + 3 * gth;
        float* lg = work + 4 * gth;        // logits, 4*gth
        unsigned short* xsS = (unsigned short*)(work + 8 * gth);  // 3 planes
        asplit_kernel<<<dim3((unsigned)(gth / 2048)), blk, 0, stream>>>(
            bufX + (size_t)g0 * TH, xsS, gth, gth);
        // fused QKV (A pre-split, B pre-split), fp32 scatter epilogue
        mgemm<true, true><<<dim3(12, rows / 128, 1), blk, 0, stream>>>(
            nullptr, xsS, gth,
            nullptr, qkvT, 786432LL,
            qg, nullptr, nullptr,
            rows, 1536, Hc, Hc, 512, 0,
            0, 0, 0, 0, gth, 0, 1.f, F_QKV);
        // logits = q.k^T / sqrt(dh)
        mgemm<false, false><<<dim3(Tc / 128, Tc / 128, g * HEADSc), blk, 0, stream>>>(
            qg, nullptr, 0, kg, nullptr, 0,
            lg, nullptr, nullptr,
            Tc, Tc, DH, Hc, Hc, Tc,
            (long long)TH, DH, (long long)TH, DH,
            (long long)HEADSc * TT, TT, sq, F_DIV);
        softmax_kernel<<<dim3(g * HEADSc * Tc), blk, 0, stream>>>(lg);
        // o = P @ V  (B = vT fp32 [d][t])
        mgemm<false, false><<<dim3(1, Tc / 128, g * HEADSc), blk, 0, stream>>>(
            lg, nullptr, 0, vT, nullptr, 0,
            og, nullptr, nullptr,
            Tc, DH, Tc, Tc, Tc, Hc,
            (long long)HEADSc * TT, TT,
            (long long)TH, (long long)DH * Tc,
            (long long)TH, DH, 1.f, 0);
        // attn_out = o @ Wo
        mgemm<false, true><<<dim3(Hc / 128, rows / 128, 1), blk, 0, stream>>>(
            og, nullptr, 0, nullptr, WoT, 262144LL,
            bufY + (size_t)g0 * TH, nullptr, nullptr,
            rows, Hc, Hc, Hc, 512, Hc,
            0, 0, 0, 0, 0, 0, 1.f, 0);
    }

    // ---- 3. x1 = LN(x + attn_out) in-place in bufX ----
    add_ln_kernel<<<dim3(M), blk, 0, stream>>>(bufX, bufY, ln1_g, ln1_b, bufX);

    // ---- 4. FFN ----
    unsigned short* x1S = (unsigned short*)work;
    float* hbuf = work + (ASP1 ? X1S_F : 0);
    if (ASP1) {
        asplit_kernel<<<dim3(M * 512 / 2048), blk, 0, stream>>>(
            bufX, x1S, (long long)M * 512, (long long)M * 512);
    }
    int nChunks = 2048 / Nc;
    for (int c = 0; c < nChunks; c++) {
        if (ASP1) {
            mgemm<true, true><<<dim3(Nc / 128, M / 128, 1), blk, 0, stream>>>(
                nullptr, x1S, (long long)M * 512,
                nullptr, W1T + (size_t)c * Nc * 512, 1048576LL,
                hbuf, b1 + c * Nc, nullptr,
                M, Nc, Hc, Hc, 512, Nc,
                0, 0, 0, 0, 0, 0, 1.f, F_BIAS | F_RELU);
        } else {
            mgemm<false, true><<<dim3(Nc / 128, M / 128, 1), blk, 0, stream>>>(
                bufX, nullptr, 0,
                nullptr, W1T + (size_t)c * Nc * 512, 1048576LL,
                hbuf, b1 + c * Nc, nullptr,
                M, Nc, Hc, Hc, 512, Nc,
                0, 0, 0, 0, 0, 0, 1.f, F_BIAS | F_RELU);
        }
        mgemm<false, true><<<dim3(Hc / 128, M / 128, 1), blk, 0, stream>>>(
            hbuf, nullptr, 0,
            nullptr, W2T + (size_t)c * Nc, 1048576LL,
            bufY, b2, nullptr,
            M, Hc, Nc, Nc, 2048, Hc,
            0, 0, 0, 0, 0, 0, 1.f, (c == 0) ? F_BIAS : F_ADDC);
    }

    // ---- 5. x2 = LN(x1 + f) in-place in bufX ----
    add_ln_kernel<<<dim3(M), blk, 0, stream>>>(bufX, bufY, ln2_g, ln2_b, bufX);

    // ---- 6. emissions ----
    em_kernel<<<dim3(M / 16), blk, 0, stream>>>(bufX, loc_W, loc_b, work);

    // ---- 7. viterbi ----
    viterbi_kernel<<<dim3(Bc), dim3(64), 0, stream>>>(
        work, start_trans, end_trans, trans, (int*)d_out);
}